// Round 2
// baseline (4633.722 us; speedup 1.0000x reference)
//
#include <hip/hip_runtime.h>
#include <hip/hip_bf16.h>
#include <stdint.h>

typedef uint32_t u32;

#define DELTAF 1e-6f
#define CLIPF 20.0f

__device__ __forceinline__ float bl(u32 u) { return __uint_as_float(u << 16); }
__device__ __forceinline__ float bh(u32 u) { return __uint_as_float(u & 0xffff0000u); }

__device__ __forceinline__ float sigf(float x) { return 1.f / (1.f + expf(-x)); }
__device__ __forceinline__ float softplusf(float x) { return fmaxf(x, 0.f) + log1pf(expf(-fabsf(x))); }

// f32 -> bf16 bits, round-to-nearest-even
__device__ __forceinline__ u32 f2b(float f) {
  u32 b = __float_as_uint(f);
  return (b + 0x7fffu + ((b >> 16) & 1u)) >> 16;
}

// load 64 consecutive f32 into registers
__device__ __forceinline__ void ldrow64f(float* wf, const float* p) {
  const float4* q = (const float4*)p;
#pragma unroll
  for (int i = 0; i < 16; ++i) {
    float4 v = q[i];
    wf[4*i+0] = v.x; wf[4*i+1] = v.y; wf[4*i+2] = v.z; wf[4*i+3] = v.w;
  }
}

// load 128 consecutive f32, convert to bf16 (RNE), pack pairs into 64 u32
__device__ __forceinline__ void ldrow128pk(u32* w, const float* p) {
  const float4* q = (const float4*)p;
#pragma unroll
  for (int i = 0; i < 32; ++i) {
    float4 v = q[i];
    w[2*i]   = f2b(v.x) | (f2b(v.y) << 16);
    w[2*i+1] = f2b(v.z) | (f2b(v.w) << 16);
  }
}

__device__ __forceinline__ float dotf64(const float* w, const float* x) {
  float a = 0.f;
#pragma unroll
  for (int i = 0; i < 16; ++i) {
    float4 xv = ((const float4*)x)[i];
    a = fmaf(w[4*i+0], xv.x, a);
    a = fmaf(w[4*i+1], xv.y, a);
    a = fmaf(w[4*i+2], xv.z, a);
    a = fmaf(w[4*i+3], xv.w, a);
  }
  return a;
}

__device__ __forceinline__ float dotp128(const u32* w, const float* x) {
  float a = 0.f;
#pragma unroll
  for (int i = 0; i < 32; ++i) {
    float4 xv = ((const float4*)x)[i];
    u32 p = w[2*i], q = w[2*i+1];
    a = fmaf(bl(p), xv.x, a);
    a = fmaf(bh(p), xv.y, a);
    a = fmaf(bl(q), xv.z, a);
    a = fmaf(bh(q), xv.w, a);
  }
  return a;
}

// dot over 4*n4 elements, f32 weights streamed from global (16B-aligned rows)
__device__ __forceinline__ float dotgf(const float* row, const float* x, int n4) {
  float a = 0.f;
  for (int i = 0; i < n4; ++i) {
    float4 w = ((const float4*)row)[i];
    float4 xv = ((const float4*)x)[i];
    a = fmaf(w.x, xv.x, a);
    a = fmaf(w.y, xv.y, a);
    a = fmaf(w.z, xv.z, a);
    a = fmaf(w.w, xv.w, a);
  }
  return a;
}

// ---------------- prep: gi_emb[t] = Wih[:, :64] @ emb[seq[t]] + bih ----------------
__global__ void prep_enc(const float* __restrict__ emb, const int* __restrict__ seq,
                         const float* __restrict__ Wih, const float* __restrict__ bih,
                         float* __restrict__ giE)
{
  __shared__ __align__(16) float sx[64];
  const int it = blockIdx.x, t = threadIdx.x;
  if (t < 64) sx[t] = emb[(size_t)seq[it]*64 + t];
  __syncthreads();
  if (t < 192) giE[it*192 + t] = bih[t] + dotgf(Wih + (size_t)t*128, sx, 16);
}

__global__ void prep_dec(const float* __restrict__ emb2, const int* __restrict__ seq3,
                         const float* __restrict__ Wih, const float* __restrict__ bih,
                         float* __restrict__ giE)
{
  __shared__ __align__(16) float sx[64];
  const int it = blockIdx.x, t = threadIdx.x;
  const int tok = (it == 0) ? 136 : seq3[it-1];
  if (t < 64) sx[t] = emb2[(size_t)tok*64 + t];
  __syncthreads();
  if (t < 384) giE[it*384 + t] = bih[t] + dotgf(Wih + (size_t)t*192, sx, 16);
}

// ---------------- encoder: 512 sequential DNC steps, 1 block per encoder ----------------
// state layout in stout per encoder (1440 f32):
//  [0,64) h | [64,128) lr | [128,144) rw | [144,160) mem row norms | [160,1184) mem | [1184,1440) link
__global__ __launch_bounds__(512) void enc_kernel(
    const float* __restrict__ Wih1, const float* __restrict__ Whh1, const float* __restrict__ bhh1,
    const float* __restrict__ iW1, const float* __restrict__ ib1,
    const float* __restrict__ Wih2, const float* __restrict__ Whh2, const float* __restrict__ bhh2,
    const float* __restrict__ iW2, const float* __restrict__ ib2,
    const float* __restrict__ giE_all, float* __restrict__ stout)
{
  __shared__ __align__(16) float s_h[64];
  __shared__ __align__(16) float s_hc[64];
  __shared__ __align__(16) float s_lr[64];
  __shared__ float s_gi[192], s_gh[192], s_xi[264];
  __shared__ __align__(16) float s_mem[16][64];
  __shared__ float s_link[16][16];
  __shared__ float s_prec[2][16];
  __shared__ float s_rw[16], s_ww[16], s_usage[16];
  __shared__ float s_norm[16], s_norm2[16], s_sim[16], s_fw[16], s_bw[16];
  __shared__ float s_rk[64], s_wk[64], s_ev[64], s_wv[64];
  __shared__ float s_sc[8]; // 0:rs 1:ws 2:fg 3:ag 4:wg 5..7:rm
  __shared__ float s_bhh[192], s_ib[264];
  __shared__ float s_wkn, s_rkn, s_S;

  const int t = threadIdx.x;
  const int e = blockIdx.x;
  const float* Wih = e ? Wih2 : Wih1;
  const float* Whh = e ? Whh2 : Whh1;
  const float* bhh = e ? bhh2 : bhh1;
  const float* iW  = e ? iW2  : iW1;
  const float* ib  = e ? ib2  : ib1;
  const float* giE = giE_all + (size_t)e * 512 * 192;

  float w1[64];  // t<192: Wih row t cols 64..127 ; t in [192,384): Whh row t-192
  float w2[64];  // t<264: iW row t
  if (t < 192)      ldrow64f(w1, Wih + (size_t)t*128 + 64);
  else if (t < 384) ldrow64f(w1, Whh + (size_t)(t-192)*64);
  if (t < 264)      ldrow64f(w2, iW + (size_t)t*64);

  if (t < 192) s_bhh[t] = bhh[t];
  if (t < 264) s_ib[t]  = ib[t];
  if (t < 64) { s_h[t] = 0.f; s_lr[t] = 0.f; }
  if (t < 16) {
    s_rw[t] = DELTAF; s_ww[t] = DELTAF; s_usage[t] = 0.f;
    s_prec[0][t] = 0.f; s_prec[1][t] = 0.f;
  }
  { float* mf = &s_mem[0][0]; for (int i = t; i < 1024; i += 512) mf[i] = 0.f; }
  if (t < 256) (&s_link[0][0])[t] = 0.f;
  __syncthreads();

  int pb = 0;
  for (int it = 0; it < 512; ++it) {
    // P1: gi (lr half) and gh GEMVs, register-resident weights
    if (t < 192) {
      s_gi[t] = giE[it*192 + t] + dotf64(w1, s_lr);
    } else if (t < 384) {
      s_gh[t-192] = s_bhh[t-192] + dotf64(w1, s_h);
    }
    __syncthreads();
    // P2: GRU combine + pre-write memory row norms
    if (t < 64) {
      float r = sigf(s_gi[t] + s_gh[t]);
      float z = sigf(s_gi[64+t] + s_gh[64+t]);
      float n = tanhf(s_gi[128+t] + r*s_gh[128+t]);
      float h = (1.f - z)*n + z*s_h[t];
      s_h[t] = h;
      s_hc[t] = fminf(fmaxf(h, -CLIPF), CLIPF);
    } else if (t < 320) {
      int g = (t-64) >> 4, l = (t-64) & 15;
      float p = 0.f;
#pragma unroll
      for (int i = 0; i < 4; ++i) { float v = s_mem[g][l*4+i]; p = fmaf(v, v, p); }
      p += __shfl_xor(p,1); p += __shfl_xor(p,2); p += __shfl_xor(p,4); p += __shfl_xor(p,8);
      if (l == 0) s_norm[g] = sqrtf(p);
    }
    __syncthreads();
    // P3: interface GEMV
    if (t < 264) s_xi[t] = s_ib[t] + dotf64(w2, s_hc);
    __syncthreads();
    // P4: interface activations
    if (t < 64) {
      s_rk[t] = tanhf(s_xi[t]);
      s_wk[t] = tanhf(s_xi[65+t]);
      s_ev[t] = sigf(s_xi[130+t]);
      s_wv[t] = tanhf(s_xi[194+t]);
    } else if (t == 64) s_sc[0] = softplusf(s_xi[64]);
    else if (t == 65) s_sc[1] = softplusf(s_xi[129]);
    else if (t == 66) s_sc[2] = sigf(s_xi[258]);
    else if (t == 67) s_sc[3] = sigf(s_xi[259]);
    else if (t == 68) s_sc[4] = sigf(s_xi[260]);
    else if (t == 69) {
      float a = s_xi[261], b = s_xi[262], c = s_xi[263];
      float mx = fmaxf(a, fmaxf(b, c));
      float ea = expf(a-mx), eb = expf(b-mx), ec = expf(c-mx);
      float s = ea + eb + ec;
      s_sc[5] = ea/s; s_sc[6] = eb/s; s_sc[7] = ec/s;
    }
    __syncthreads();
    // P5: usage update + key norms
    if (t < 16) {
      float u = s_usage[t];
      u = u + (1.f - u) * s_ww[t];
      u = u * (1.f - s_sc[2] * s_rw[t]);
      s_usage[t] = u;
    } else if (t >= 64 && t < 128) {
      int l = t - 64;
      float v = s_wk[l], p = v*v;
      p += __shfl_xor(p,1); p += __shfl_xor(p,2); p += __shfl_xor(p,4);
      p += __shfl_xor(p,8); p += __shfl_xor(p,16); p += __shfl_xor(p,32);
      if (l == 0) s_wkn = sqrtf(p);
    } else if (t >= 128 && t < 192) {
      int l = t - 128;
      float v = s_rk[l], p = v*v;
      p += __shfl_xor(p,1); p += __shfl_xor(p,2); p += __shfl_xor(p,4);
      p += __shfl_xor(p,8); p += __shfl_xor(p,16); p += __shfl_xor(p,32);
      if (l == 0) s_rkn = sqrtf(p);
    }
    __syncthreads();
    // P6: write-key content similarity (pre-write memory)
    {
      int m = t >> 5, l = t & 31;
      float p = fmaf(s_wk[l], s_mem[m][l], s_wk[l+32]*s_mem[m][l+32]);
      p += __shfl_xor(p,1); p += __shfl_xor(p,2); p += __shfl_xor(p,4);
      p += __shfl_xor(p,8); p += __shfl_xor(p,16);
      if (l == 0) s_sim[m] = p / ((s_norm[m] + DELTAF) * (s_wkn + DELTAF)) * s_sc[1];
    }
    __syncthreads();
    // P7: softmax + allocation + write weights (lanes 0..15 of wave 0)
    if (t < 16) {
      float x = s_sim[t];
      float mx = x;
      mx = fmaxf(mx, __shfl_xor(mx,1)); mx = fmaxf(mx, __shfl_xor(mx,2));
      mx = fmaxf(mx, __shfl_xor(mx,4)); mx = fmaxf(mx, __shfl_xor(mx,8));
      float ex = expf(x - mx);
      float sm = ex;
      sm += __shfl_xor(sm,1); sm += __shfl_xor(sm,2); sm += __shfl_xor(sm,4); sm += __shfl_xor(sm,8);
      float wcw = ex / sm;
      float um = DELTAF + (1.f - DELTAF) * s_usage[t];
      float prod = 1.f;
#pragma unroll
      for (int j = 0; j < 16; ++j) {
        float uj = DELTAF + (1.f - DELTAF) * s_usage[j];
        bool before = (uj < um) || ((uj == um) && (j < t));  // stable argsort order
        prod *= before ? uj : 1.f;
      }
      float alloc = (1.f - um) * prod;
      float ww = s_sc[4] * (s_sc[3]*alloc + (1.f - s_sc[3])*wcw);
      float S = ww;
      S += __shfl_xor(S,1); S += __shfl_xor(S,2); S += __shfl_xor(S,4); S += __shfl_xor(S,8);
      s_ww[t] = ww;
      if (t == 0) s_S = S;
    }
    __syncthreads();
    // P8: memory write + link + precedence (double-buffered prec)
    {
#pragma unroll
      for (int q = 0; q < 2; ++q) {
        int idx = t + q*512;
        int m = idx >> 6, wi = idx & 63;
        float wwm = s_ww[m];
        s_mem[m][wi] = s_mem[m][wi] * (1.f - wwm * s_ev[wi]) + wwm * s_wv[wi];
      }
    }
    if (t < 256) {
      int i = t >> 4, j = t & 15;
      float lv = (i == j) ? 0.f
               : ((1.f - s_ww[i] - s_ww[j]) * s_link[i][j] + s_ww[i] * s_prec[pb][j]);
      s_link[i][j] = lv;
    } else if (t < 272) {
      int j = t - 256;
      s_prec[pb^1][j] = (1.f - s_S) * s_prec[pb][j] + s_ww[j];
    }
    __syncthreads();
    // P9: post-write norms + forward/backward weightings (old rw)
    if (t < 256) {
      int m = t >> 4, l = t & 15;
      float p = 0.f;
#pragma unroll
      for (int i = 0; i < 4; ++i) { float v = s_mem[m][l*4+i]; p = fmaf(v, v, p); }
      p += __shfl_xor(p,1); p += __shfl_xor(p,2); p += __shfl_xor(p,4); p += __shfl_xor(p,8);
      if (l == 0) s_norm2[m] = sqrtf(p);
    } else if (t < 272) {
      int i = t - 256;
      float a = 0.f;
#pragma unroll
      for (int j = 0; j < 16; ++j) a = fmaf(s_link[i][j], s_rw[j], a);
      s_fw[i] = a;
    } else if (t < 288) {
      int i = t - 272;
      float a = 0.f;
#pragma unroll
      for (int j = 0; j < 16; ++j) a = fmaf(s_link[j][i], s_rw[j], a);
      s_bw[i] = a;
    }
    __syncthreads();
    // P10: read-key content similarity (post-write memory)
    {
      int m = t >> 5, l = t & 31;
      float p = fmaf(s_rk[l], s_mem[m][l], s_rk[l+32]*s_mem[m][l+32]);
      p += __shfl_xor(p,1); p += __shfl_xor(p,2); p += __shfl_xor(p,4);
      p += __shfl_xor(p,8); p += __shfl_xor(p,16);
      if (l == 0) s_sim[m] = p / ((s_norm2[m] + DELTAF) * (s_rkn + DELTAF)) * s_sc[0];
    }
    __syncthreads();
    // P11: read softmax + new read weights
    if (t < 16) {
      float x = s_sim[t];
      float mx = x;
      mx = fmaxf(mx, __shfl_xor(mx,1)); mx = fmaxf(mx, __shfl_xor(mx,2));
      mx = fmaxf(mx, __shfl_xor(mx,4)); mx = fmaxf(mx, __shfl_xor(mx,8));
      float ex = expf(x - mx);
      float sm = ex;
      sm += __shfl_xor(sm,1); sm += __shfl_xor(sm,2); sm += __shfl_xor(sm,4); sm += __shfl_xor(sm,8);
      float cw = ex / sm;
      s_rw[t] = s_sc[5]*s_bw[t] + s_sc[6]*s_fw[t] + s_sc[7]*cw;
    }
    __syncthreads();
    // P12: read vector
    if (t < 64) {
      float a = 0.f;
#pragma unroll
      for (int m = 0; m < 16; ++m) a = fmaf(s_rw[m], s_mem[m][t], a);
      s_lr[t] = a;
    }
    pb ^= 1;
    __syncthreads();
  }

  float* so = stout + (size_t)e * 1440;
  if (t < 64) { so[t] = s_h[t]; so[64+t] = s_lr[t]; }
  if (t < 16) { so[128+t] = s_rw[t]; so[144+t] = s_norm2[t]; }
  { const float* mf = &s_mem[0][0]; for (int i = t; i < 1024; i += 512) so[160+i] = mf[i]; }
  if (t < 256) so[1184+t] = (&s_link[0][0])[t];
}

// ---------------- decoder: 65 sequential steps, both memories read in parallel halves ----------------
__global__ __launch_bounds__(512) void dec_kernel(
    const float* __restrict__ Wih, const float* __restrict__ Whh, const float* __restrict__ bhh,
    const float* __restrict__ ifw, const float* __restrict__ ifwb,
    const float* __restrict__ giE, const float* __restrict__ st, float* __restrict__ r12h)
{
  __shared__ __align__(16) float s_h[128];
  __shared__ __align__(16) float s_r12[128];
  __shared__ float s_gi[384], s_gh[384], s_xi[136];
  __shared__ __align__(16) float s_mem[2][16][64];
  __shared__ float s_link[2][16][16];
  __shared__ float s_rw[2][16], s_norm[2][16];
  __shared__ float s_sim[2][16], s_fw[2][16], s_bw[2][16];
  __shared__ float s_rk[2][64];
  __shared__ float s_rs[2], s_rkn[2];
  __shared__ float s_rm[2][3];
  __shared__ float s_bhh[384], s_ifwb[136];

  const int t = threadIdx.x;

  u32 w1[64], w2[64];
  if (t < 384) {
    ldrow128pk(w1, Wih + (size_t)t*192 + 64);  // x-part = [r1;r2]
    ldrow128pk(w2, Whh + (size_t)t*128);
  } else {
    ldrow128pk(w1, ifw + (size_t)(t-384)*128);
    if (t < 392) ldrow128pk(w2, ifw + (size_t)(t-256)*128);  // rows 128..135
  }
  if (t < 384) s_bhh[t]  = bhh[t];
  if (t < 136) s_ifwb[t] = ifwb[t];
  if (t < 64) {
    s_h[t]      = st[t];        s_h[64+t]   = st[1440+t];
    s_r12[t]    = st[64+t];     s_r12[64+t] = st[1440+64+t];
  }
  if (t < 16) {
    s_rw[0][t]   = st[128+t];   s_rw[1][t]   = st[1440+128+t];
    s_norm[0][t] = st[144+t];   s_norm[1][t] = st[1440+144+t];
  }
  for (int i = t; i < 1024; i += 512) {
    (&s_mem[0][0][0])[i] = st[160+i];
    (&s_mem[1][0][0])[i] = st[1440+160+i];
  }
  if (t < 256) {
    (&s_link[0][0][0])[t] = st[1184+t];
    (&s_link[1][0][0])[t] = st[1440+1184+t];
  }
  __syncthreads();

  for (int it = 0; it < 65; ++it) {
    // P1: gi (r1r2 half) + gh
    if (t < 384) {
      s_gi[t] = giE[it*384 + t] + dotp128(w1, s_r12);
      s_gh[t] = s_bhh[t] + dotp128(w2, s_h);
    }
    __syncthreads();
    // P2: GRU (H=128, no clip)
    if (t < 128) {
      float r = sigf(s_gi[t] + s_gh[t]);
      float z = sigf(s_gi[128+t] + s_gh[128+t]);
      float n = tanhf(s_gi[256+t] + r*s_gh[256+t]);
      s_h[t] = (1.f - z)*n + z*s_h[t];
    }
    __syncthreads();
    // P3: interface GEMV (136 rows on threads 384..511)
    if (t >= 384) {
      s_xi[t-384] = s_ifwb[t-384] + dotp128(w1, s_h);
      if (t < 392) s_xi[t-256] = s_ifwb[t-256] + dotp128(w2, s_h);
    }
    __syncthreads();
    // P4: activations
    if (t < 128) {
      s_rk[t>>6][t&63] = tanhf(s_xi[t]);
    } else if (t == 128 || t == 129) {
      s_rs[t-128] = softplusf(s_xi[t]);
    } else if (t == 130 || t == 131) {
      int hh = t - 130;
      float a = s_xi[130 + hh*3], b = s_xi[131 + hh*3], c = s_xi[132 + hh*3];
      float mx = fmaxf(a, fmaxf(b, c));
      float ea = expf(a-mx), eb = expf(b-mx), ec = expf(c-mx);
      float s = ea+eb+ec;
      s_rm[hh][0] = ea/s; s_rm[hh][1] = eb/s; s_rm[hh][2] = ec/s;
    }
    __syncthreads();
    // P5: rk norm + fw/bw per half
    {
      int half = t >> 8, u = t & 255;
      if (u < 64) {
        float v = s_rk[half][u], p = v*v;
        p += __shfl_xor(p,1); p += __shfl_xor(p,2); p += __shfl_xor(p,4);
        p += __shfl_xor(p,8); p += __shfl_xor(p,16); p += __shfl_xor(p,32);
        if (u == 0) s_rkn[half] = sqrtf(p);
      } else if (u < 80) {
        int i = u - 64;
        float a = 0.f;
#pragma unroll
        for (int j = 0; j < 16; ++j) a = fmaf(s_link[half][i][j], s_rw[half][j], a);
        s_fw[half][i] = a;
      } else if (u < 96) {
        int i = u - 80;
        float a = 0.f;
#pragma unroll
        for (int j = 0; j < 16; ++j) a = fmaf(s_link[half][j][i], s_rw[half][j], a);
        s_bw[half][i] = a;
      }
    }
    __syncthreads();
    // P6: content similarity per half
    {
      int half = t >> 8, u = t & 255;
      int m = u >> 4, l = u & 15;
      float p = 0.f;
#pragma unroll
      for (int i = 0; i < 4; ++i) p = fmaf(s_rk[half][l*4+i], s_mem[half][m][l*4+i], p);
      p += __shfl_xor(p,1); p += __shfl_xor(p,2); p += __shfl_xor(p,4); p += __shfl_xor(p,8);
      if (l == 0) s_sim[half][m] = p / ((s_norm[half][m] + DELTAF)*(s_rkn[half] + DELTAF)) * s_rs[half];
    }
    __syncthreads();
    // P7: softmax + new read weights
    {
      int half = t >> 8, u = t & 255;
      if (u < 16) {
        float x = s_sim[half][u];
        float mx = x;
        mx = fmaxf(mx, __shfl_xor(mx,1)); mx = fmaxf(mx, __shfl_xor(mx,2));
        mx = fmaxf(mx, __shfl_xor(mx,4)); mx = fmaxf(mx, __shfl_xor(mx,8));
        float ex = expf(x - mx);
        float sm = ex;
        sm += __shfl_xor(sm,1); sm += __shfl_xor(sm,2); sm += __shfl_xor(sm,4); sm += __shfl_xor(sm,8);
        float cw = ex / sm;
        s_rw[half][u] = s_rm[half][0]*s_bw[half][u] + s_rm[half][1]*s_fw[half][u] + s_rm[half][2]*cw;
      }
    }
    __syncthreads();
    // P8: read vectors + store per-step [r1,r2,h] for deferred logits
    {
      int half = t >> 8, u = t & 255;
      if (u < 64) {
        float a = 0.f;
#pragma unroll
        for (int m = 0; m < 16; ++m) a = fmaf(s_rw[half][m], s_mem[half][m][u], a);
        s_r12[half*64 + u] = a;
        r12h[it*256 + half*64 + u] = a;
      } else if (half == 0 && u >= 128) {
        r12h[it*256 + u] = s_h[u - 128];
      }
    }
    __syncthreads();
  }
}

// ---------------- deferred logits: o = [r1;r2]@r2o^T + b; logits = (o+h)@outW^T + b ----------------
__global__ void logits_kernel(
    const float* __restrict__ r2oW, const float* __restrict__ r2ob,
    const float* __restrict__ outW, const float* __restrict__ outb,
    const float* __restrict__ r12h, float* __restrict__ out)
{
  __shared__ __align__(16) float s_in[128];
  __shared__ __align__(16) float s_oh[128];
  const int it = blockIdx.x, t = threadIdx.x;
  if (t < 128) s_in[t] = r12h[it*256 + t];
  __syncthreads();
  if (t < 128) {
    float o = r2ob[t] + dotgf(r2oW + (size_t)t*128, s_in, 32);
    s_oh[t] = o + r12h[it*256 + 128 + t];
  }
  __syncthreads();
  if (t < 138) {
    out[it*138 + t] = outb[t] + dotgf(outW + (size_t)t*128, s_oh, 32);
  }
}

extern "C" void kernel_launch(void* const* d_in, const int* in_sizes, int n_in,
                              void* d_out, int out_size, void* d_ws, size_t ws_size,
                              hipStream_t stream) {
  (void)in_sizes; (void)n_in; (void)out_size; (void)ws_size;
  const float* emb0   = (const float*)d_in[0];
  const float* emb1   = (const float*)d_in[1];
  const float* emb2   = (const float*)d_in[2];
  const float* e1_Wih = (const float*)d_in[3];
  const float* e1_Whh = (const float*)d_in[4];
  const float* e1_bih = (const float*)d_in[5];
  const float* e1_bhh = (const float*)d_in[6];
  const float* e1_iW  = (const float*)d_in[7];
  const float* e1_ib  = (const float*)d_in[8];
  const float* e2_Wih = (const float*)d_in[9];
  const float* e2_Whh = (const float*)d_in[10];
  const float* e2_bih = (const float*)d_in[11];
  const float* e2_bhh = (const float*)d_in[12];
  const float* e2_iW  = (const float*)d_in[13];
  const float* e2_ib  = (const float*)d_in[14];
  const float* dWih   = (const float*)d_in[15];
  const float* dWhh   = (const float*)d_in[16];
  const float* dbih   = (const float*)d_in[17];
  const float* dbhh   = (const float*)d_in[18];
  const float* ifwW   = (const float*)d_in[19];
  const float* ifwb   = (const float*)d_in[20];
  const float* r2oW   = (const float*)d_in[21];
  const float* r2ob   = (const float*)d_in[22];
  const float* outW   = (const float*)d_in[23];
  const float* outb   = (const float*)d_in[24];
  const int* seq1     = (const int*)d_in[25];
  const int* seq2     = (const int*)d_in[26];
  const int* seq3     = (const int*)d_in[27];

  float* ws   = (float*)d_ws;
  float* giE1 = ws;                    // 512*192
  float* giE2 = giE1 + 512*192;        // 512*192 (contiguous with giE1 for enc_kernel)
  float* giEd = giE2 + 512*192;        // 65*384
  float* st   = giEd + 65*384;         // 2*1440
  float* r12h = st + 2*1440;           // 65*256

  prep_enc<<<512, 192, 0, stream>>>(emb0, seq1, e1_Wih, e1_bih, giE1);
  prep_enc<<<512, 192, 0, stream>>>(emb1, seq2, e2_Wih, e2_bih, giE2);
  prep_dec<<<65, 384, 0, stream>>>(emb2, seq3, dWih, dbih, giEd);
  enc_kernel<<<2, 512, 0, stream>>>(e1_Wih, e1_Whh, e1_bhh, e1_iW, e1_ib,
                                    e2_Wih, e2_Whh, e2_bhh, e2_iW, e2_ib, giE1, st);
  dec_kernel<<<1, 512, 0, stream>>>(dWih, dWhh, dbhh, ifwW, ifwb, giEd, st, r12h);
  logits_kernel<<<65, 256, 0, stream>>>(r2oW, r2ob, outW, outb, r12h, (float*)d_out);
}

// Round 3
// 4229.609 us; speedup vs baseline: 1.0955x; 1.0955x over previous
//
#include <hip/hip_runtime.h>
#include <hip/hip_bf16.h>
#include <stdint.h>

typedef uint32_t u32;

#define DELTAF 1e-6f
#define CLIPF 20.0f

__device__ __forceinline__ float bl(u32 u) { return __uint_as_float(u << 16); }
__device__ __forceinline__ float bh(u32 u) { return __uint_as_float(u & 0xffff0000u); }

__device__ __forceinline__ float sigf(float x) { return 1.f / (1.f + expf(-x)); }
__device__ __forceinline__ float softplusf(float x) { return fmaxf(x, 0.f) + log1pf(expf(-fabsf(x))); }

// f32 -> bf16 bits, round-to-nearest-even
__device__ __forceinline__ u32 f2b(float f) {
  u32 b = __float_as_uint(f);
  return (b + 0x7fffu + ((b >> 16) & 1u)) >> 16;
}

// load 64 consecutive f32 into registers
__device__ __forceinline__ void ldrow64f(float* wf, const float* p) {
  const float4* q = (const float4*)p;
#pragma unroll
  for (int i = 0; i < 16; ++i) {
    float4 v = q[i];
    wf[4*i+0] = v.x; wf[4*i+1] = v.y; wf[4*i+2] = v.z; wf[4*i+3] = v.w;
  }
}

// load 128 consecutive f32 -> bf16 RNE, pack pairs into 64 u32
__device__ __forceinline__ void ldrow128pk(u32* w, const float* p) {
  const float4* q = (const float4*)p;
#pragma unroll
  for (int i = 0; i < 32; ++i) {
    float4 v = q[i];
    w[2*i]   = f2b(v.x) | (f2b(v.y) << 16);
    w[2*i+1] = f2b(v.z) | (f2b(v.w) << 16);
  }
}

// load 64 consecutive f32 -> bf16 RNE, pack into 32 u32
__device__ __forceinline__ void ldrow64pk(u32* w, const float* p) {
  const float4* q = (const float4*)p;
#pragma unroll
  for (int i = 0; i < 16; ++i) {
    float4 v = q[i];
    w[2*i]   = f2b(v.x) | (f2b(v.y) << 16);
    w[2*i+1] = f2b(v.z) | (f2b(v.w) << 16);
  }
}

// 64-long dot, f32 weights in regs, 4 accumulators
__device__ __forceinline__ float dotf64(const float* w, const float* x) {
  float a0 = 0.f, a1 = 0.f, a2 = 0.f, a3 = 0.f;
#pragma unroll
  for (int i = 0; i < 16; i += 4) {
    float4 v0 = ((const float4*)x)[i+0];
    float4 v1 = ((const float4*)x)[i+1];
    float4 v2 = ((const float4*)x)[i+2];
    float4 v3 = ((const float4*)x)[i+3];
    a0 = fmaf(w[4*i+ 0], v0.x, a0); a0 = fmaf(w[4*i+ 1], v0.y, a0);
    a0 = fmaf(w[4*i+ 2], v0.z, a0); a0 = fmaf(w[4*i+ 3], v0.w, a0);
    a1 = fmaf(w[4*i+ 4], v1.x, a1); a1 = fmaf(w[4*i+ 5], v1.y, a1);
    a1 = fmaf(w[4*i+ 6], v1.z, a1); a1 = fmaf(w[4*i+ 7], v1.w, a1);
    a2 = fmaf(w[4*i+ 8], v2.x, a2); a2 = fmaf(w[4*i+ 9], v2.y, a2);
    a2 = fmaf(w[4*i+10], v2.z, a2); a2 = fmaf(w[4*i+11], v2.w, a2);
    a3 = fmaf(w[4*i+12], v3.x, a3); a3 = fmaf(w[4*i+13], v3.y, a3);
    a3 = fmaf(w[4*i+14], v3.z, a3); a3 = fmaf(w[4*i+15], v3.w, a3);
  }
  return (a0 + a1) + (a2 + a3);
}

// 128-long dot, packed bf16 weights in regs, 4 accumulators
__device__ __forceinline__ float dotp128(const u32* w, const float* x) {
  float a0 = 0.f, a1 = 0.f, a2 = 0.f, a3 = 0.f;
#pragma unroll
  for (int i = 0; i < 8; ++i) {
    float4 v0 = ((const float4*)x)[4*i+0];
    float4 v1 = ((const float4*)x)[4*i+1];
    float4 v2 = ((const float4*)x)[4*i+2];
    float4 v3 = ((const float4*)x)[4*i+3];
    u32 p0 = w[8*i+0], q0 = w[8*i+1], p1 = w[8*i+2], q1 = w[8*i+3];
    u32 p2 = w[8*i+4], q2 = w[8*i+5], p3 = w[8*i+6], q3 = w[8*i+7];
    a0 = fmaf(bl(p0), v0.x, a0); a0 = fmaf(bh(p0), v0.y, a0);
    a0 = fmaf(bl(q0), v0.z, a0); a0 = fmaf(bh(q0), v0.w, a0);
    a1 = fmaf(bl(p1), v1.x, a1); a1 = fmaf(bh(p1), v1.y, a1);
    a1 = fmaf(bl(q1), v1.z, a1); a1 = fmaf(bh(q1), v1.w, a1);
    a2 = fmaf(bl(p2), v2.x, a2); a2 = fmaf(bh(p2), v2.y, a2);
    a2 = fmaf(bl(q2), v2.z, a2); a2 = fmaf(bh(q2), v2.w, a2);
    a3 = fmaf(bl(p3), v3.x, a3); a3 = fmaf(bh(p3), v3.y, a3);
    a3 = fmaf(bl(q3), v3.z, a3); a3 = fmaf(bh(q3), v3.w, a3);
  }
  return (a0 + a1) + (a2 + a3);
}

// 64-long dot, packed bf16 weights (32 u32), 2 accumulators
__device__ __forceinline__ float dotp64(const u32* w, const float* x) {
  float a0 = 0.f, a1 = 0.f;
#pragma unroll
  for (int i = 0; i < 8; ++i) {
    float4 v0 = ((const float4*)x)[2*i+0];
    float4 v1 = ((const float4*)x)[2*i+1];
    u32 p0 = w[4*i+0], q0 = w[4*i+1], p1 = w[4*i+2], q1 = w[4*i+3];
    a0 = fmaf(bl(p0), v0.x, a0); a0 = fmaf(bh(p0), v0.y, a0);
    a0 = fmaf(bl(q0), v0.z, a0); a0 = fmaf(bh(q0), v0.w, a0);
    a1 = fmaf(bl(p1), v1.x, a1); a1 = fmaf(bh(p1), v1.y, a1);
    a1 = fmaf(bl(q1), v1.z, a1); a1 = fmaf(bh(q1), v1.w, a1);
  }
  return a0 + a1;
}

// dot over 4*n4 elements, f32 weights streamed from global
__device__ __forceinline__ float dotgf(const float* row, const float* x, int n4) {
  float a = 0.f;
  for (int i = 0; i < n4; ++i) {
    float4 w = ((const float4*)row)[i];
    float4 xv = ((const float4*)x)[i];
    a = fmaf(w.x, xv.x, a);
    a = fmaf(w.y, xv.y, a);
    a = fmaf(w.z, xv.z, a);
    a = fmaf(w.w, xv.w, a);
  }
  return a;
}

// ---------------- prep kernels ----------------
__global__ void prep_enc(const float* __restrict__ emb, const int* __restrict__ seq,
                         const float* __restrict__ Wih, const float* __restrict__ bih,
                         float* __restrict__ giE)
{
  __shared__ __align__(16) float sx[64];
  const int it = blockIdx.x, t = threadIdx.x;
  if (t < 64) sx[t] = emb[(size_t)seq[it]*64 + t];
  __syncthreads();
  if (t < 192) giE[it*192 + t] = bih[t] + dotgf(Wih + (size_t)t*128, sx, 16);
}

__global__ void prep_dec(const float* __restrict__ emb2, const int* __restrict__ seq3,
                         const float* __restrict__ Wih, const float* __restrict__ bih,
                         float* __restrict__ giE)
{
  __shared__ __align__(16) float sx[64];
  const int it = blockIdx.x, t = threadIdx.x;
  const int tok = (it == 0) ? 136 : seq3[it-1];
  if (t < 64) sx[t] = emb2[(size_t)tok*64 + t];
  __syncthreads();
  if (t < 384) giE[it*384 + t] = bih[t] + dotgf(Wih + (size_t)t*192, sx, 16);
}

// ---------------- encoder: 512 sequential DNC steps, 1 block per encoder ----------------
// stout layout per encoder (1440 f32):
//  [0,64) h | [64,128) lr | [128,144) rw | [144,160) mem row norms | [160,1184) mem | [1184,1440) link
__global__ __launch_bounds__(512, 2) void enc_kernel(
    const float* __restrict__ Wih1, const float* __restrict__ Whh1, const float* __restrict__ bhh1,
    const float* __restrict__ iW1, const float* __restrict__ ib1,
    const float* __restrict__ Wih2, const float* __restrict__ Whh2, const float* __restrict__ bhh2,
    const float* __restrict__ iW2, const float* __restrict__ ib2,
    const float* __restrict__ giE_all, float* __restrict__ stout)
{
  __shared__ __align__(16) float s_h[64];
  __shared__ __align__(16) float s_hc[64];
  __shared__ __align__(16) float s_lr[64];
  __shared__ float s_gi[192], s_gh[192], s_xi[264];
  __shared__ __align__(16) float s_mem[16][64];
  __shared__ float s_link[16][16];
  __shared__ float s_prec[2][16];
  __shared__ __align__(16) float s_rw[16];
  __shared__ __align__(16) float s_ww[16];
  __shared__ __align__(16) float s_usage[16];
  __shared__ float s_norm[16], s_sim[16], s_fw[16], s_bw[16];
  __shared__ float s_ev[64], s_wv[64];
  __shared__ float s_sc[8]; // 0:rs 1:ws 3:ag 4:wg 5..7:rm
  __shared__ float s_bhh[192], s_ib[264];
  __shared__ float s_wkn, s_rkn, s_S;

  const int t = threadIdx.x;
  const int e = blockIdx.x;
  const float* Wih = e ? Wih2 : Wih1;
  const float* Whh = e ? Whh2 : Whh1;
  const float* bhh = e ? bhh2 : bhh1;
  const float* iW  = e ? iW2  : iW1;
  const float* ib  = e ? ib2  : ib1;
  const float* giE = giE_all + (size_t)e * 512 * 192;

  float w1[64];  // t<192: Wih row t cols 64..127 ; t in [192,384): Whh row t-192
  float w2[64];  // t<264: iW row t
  if (t < 192)      ldrow64f(w1, Wih + (size_t)t*128 + 64);
  else if (t < 384) ldrow64f(w1, Whh + (size_t)(t-192)*64);
  if (t < 264)      ldrow64f(w2, iW + (size_t)t*64);

  if (t < 192) s_bhh[t] = bhh[t];
  if (t < 264) s_ib[t]  = ib[t];
  if (t < 64) { s_h[t] = 0.f; s_lr[t] = 0.f; }
  if (t < 16) {
    s_rw[t] = DELTAF; s_ww[t] = DELTAF; s_usage[t] = 0.f; s_norm[t] = 0.f;
    s_prec[0][t] = 0.f; s_prec[1][t] = 0.f;
  }
  { float* mf = &s_mem[0][0]; for (int i = t; i < 1024; i += 512) mf[i] = 0.f; }
  if (t < 256) (&s_link[0][0])[t] = 0.f;
  __syncthreads();

  float gcur = (t < 192) ? giE[t] : 0.f;   // prefetched gi_emb for step 0
  int pb = 0;

  for (int it = 0; it < 512; ++it) {
    // ---- P1: gi (lr half) and gh GEMVs, register-resident weights ----
    if (t < 192) {
      int nx = (it + 1 < 512) ? (it + 1) : 511;
      float gn = giE[nx*192 + t];              // prefetch next step (latency hidden)
      s_gi[t] = gcur + dotf64(w1, s_lr);
      gcur = gn;
    } else if (t < 384) {
      s_gh[t-192] = s_bhh[t-192] + dotf64(w1, s_h);
    }
    __syncthreads();
    // ---- P2: GRU combine ----
    if (t < 64) {
      float r = sigf(s_gi[t] + s_gh[t]);
      float z = sigf(s_gi[64+t] + s_gh[64+t]);
      float n = tanhf(s_gi[128+t] + r*s_gh[128+t]);
      float h = (1.f - z)*n + z*s_h[t];
      s_h[t] = h;
      s_hc[t] = fminf(fmaxf(h, -CLIPF), CLIPF);
    }
    __syncthreads();
    // ---- P3: interface GEMV ----
    if (t < 264) s_xi[t] = s_ib[t] + dotf64(w2, s_hc);
    __syncthreads();
    // ---- S1: write-key sim (raw) + activations + key norms + usage + scalars ----
    {
      int m = t >> 5, l = t & 31;
      float wkl = tanhf(s_xi[65+l]);
      float wkh = tanhf(s_xi[65+32+l]);
      float p = fmaf(wkl, s_mem[m][l], wkh * s_mem[m][l+32]);
      p += __shfl_xor(p,1); p += __shfl_xor(p,2); p += __shfl_xor(p,4);
      p += __shfl_xor(p,8); p += __shfl_xor(p,16);
      if (l == 0) s_sim[m] = p;   // raw dot; normalized in S2
    }
    if (t < 64) {
      s_ev[t] = sigf(s_xi[130+t]);
      s_wv[t] = tanhf(s_xi[194+t]);
    } else if (t < 128) {
      int l = t - 64;                       // wave 1: read-key norm
      float v = tanhf(s_xi[l]);
      float p = v*v;
      p += __shfl_xor(p,1); p += __shfl_xor(p,2); p += __shfl_xor(p,4);
      p += __shfl_xor(p,8); p += __shfl_xor(p,16); p += __shfl_xor(p,32);
      if (l == 0) s_rkn = sqrtf(p);
    } else if (t < 192) {
      int l = t - 128;                      // wave 2: write-key norm
      float v = tanhf(s_xi[65+l]);
      float p = v*v;
      p += __shfl_xor(p,1); p += __shfl_xor(p,2); p += __shfl_xor(p,4);
      p += __shfl_xor(p,8); p += __shfl_xor(p,16); p += __shfl_xor(p,32);
      if (l == 0) s_wkn = sqrtf(p);
    } else if (t < 208) {
      int j = t - 192;                      // usage update (prev ww, prev rw, this fg)
      float fg = sigf(s_xi[258]);
      float u = s_usage[j];
      u = u + (1.f - u) * s_ww[j];
      u = u * (1.f - fg * s_rw[j]);
      s_usage[j] = u;
    } else if (t == 208) s_sc[0] = softplusf(s_xi[64]);
    else if (t == 209) s_sc[1] = softplusf(s_xi[129]);
    else if (t == 210) s_sc[3] = sigf(s_xi[259]);
    else if (t == 211) s_sc[4] = sigf(s_xi[260]);
    else if (t == 212) {
      float a = s_xi[261], b = s_xi[262], c = s_xi[263];
      float mx = fmaxf(a, fmaxf(b, c));
      float ea = expf(a-mx), eb = expf(b-mx), ec = expf(c-mx);
      float s = ea + eb + ec;
      s_sc[5] = ea/s; s_sc[6] = eb/s; s_sc[7] = ec/s;
    }
    __syncthreads();
    // ---- S2: write softmax + allocation + write weights (wave 0, lanes 0..15) ----
    if (t < 16) {
      float x = s_sim[t] / ((s_norm[t] + DELTAF) * (s_wkn + DELTAF)) * s_sc[1];
      float mx = x;
      mx = fmaxf(mx, __shfl_xor(mx,1)); mx = fmaxf(mx, __shfl_xor(mx,2));
      mx = fmaxf(mx, __shfl_xor(mx,4)); mx = fmaxf(mx, __shfl_xor(mx,8));
      float ex = expf(x - mx);
      float sm = ex;
      sm += __shfl_xor(sm,1); sm += __shfl_xor(sm,2); sm += __shfl_xor(sm,4); sm += __shfl_xor(sm,8);
      float wcw = ex / sm;
      float4 u0 = ((const float4*)s_usage)[0];
      float4 u1 = ((const float4*)s_usage)[1];
      float4 u2 = ((const float4*)s_usage)[2];
      float4 u3 = ((const float4*)s_usage)[3];
      float uj[16] = {u0.x,u0.y,u0.z,u0.w, u1.x,u1.y,u1.z,u1.w,
                      u2.x,u2.y,u2.z,u2.w, u3.x,u3.y,u3.z,u3.w};
      float um = DELTAF + (1.f - DELTAF) * s_usage[t];
      float prod = 1.f;
#pragma unroll
      for (int j = 0; j < 16; ++j) {
        float v = DELTAF + (1.f - DELTAF) * uj[j];
        bool before = (v < um) || ((v == um) && (j < t));  // stable argsort order
        prod *= before ? v : 1.f;
      }
      float alloc = (1.f - um) * prod;
      float ww = s_sc[4] * (s_sc[3]*alloc + (1.f - s_sc[3])*wcw);
      float S = ww;
      S += __shfl_xor(S,1); S += __shfl_xor(S,2); S += __shfl_xor(S,4); S += __shfl_xor(S,8);
      s_ww[t] = ww;
      if (t == 0) s_S = S;
    }
    __syncthreads();
    // ---- S3: memory write + link update (+in-register fw) + precedence ----
    {
#pragma unroll
      for (int q = 0; q < 2; ++q) {
        int idx = t + q*512;
        int m = idx >> 6, wi = idx & 63;
        float wwm = s_ww[m];
        s_mem[m][wi] = s_mem[m][wi] * (1.f - wwm * s_ev[wi]) + wwm * s_wv[wi];
      }
    }
    if (t < 256) {
      int i = t >> 4, j = t & 15;
      float lv = (i == j) ? 0.f
               : ((1.f - s_ww[i] - s_ww[j]) * s_link[i][j] + s_ww[i] * s_prec[pb][j]);
      s_link[i][j] = lv;
      // fw_i = sum_j lv * rw_old[j]  (16-lane subgroup reduce, wave-local)
      float p = lv * s_rw[j];
      p += __shfl_xor(p,1); p += __shfl_xor(p,2); p += __shfl_xor(p,4); p += __shfl_xor(p,8);
      if (j == 0) s_fw[i] = p;
    } else if (t < 272) {
      int j = t - 256;
      s_prec[pb^1][j] = (1.f - s_S) * s_prec[pb][j] + s_ww[j];
    }
    __syncthreads();
    // ---- S4: read-key sim (raw) + post-write norms (dual reduce) + bw ----
    {
      int m = t >> 5, l = t & 31;
      float rkl = tanhf(s_xi[l]);
      float rkh = tanhf(s_xi[l+32]);
      float ml = s_mem[m][l], mh = s_mem[m][l+32];
      float p = fmaf(rkl, ml, rkh * mh);
      float q = fmaf(ml, ml, mh * mh);
      p += __shfl_xor(p,1);  q += __shfl_xor(q,1);
      p += __shfl_xor(p,2);  q += __shfl_xor(q,2);
      p += __shfl_xor(p,4);  q += __shfl_xor(q,4);
      p += __shfl_xor(p,8);  q += __shfl_xor(q,8);
      p += __shfl_xor(p,16); q += __shfl_xor(q,16);
      if (l == 0) { s_sim[m] = p; s_norm[m] = sqrtf(q); }  // s_norm now = post-write norm (carried)
    }
    if (t >= 496) {
      int i = t - 496;   // bw_i = sum_j link[j][i] * rw_old[j]
      float a = 0.f;
#pragma unroll
      for (int j = 0; j < 16; ++j) a = fmaf(s_link[j][i], s_rw[j], a);
      s_bw[i] = a;
    }
    __syncthreads();
    // ---- S5: read softmax + read weights + read vector (wave 0) ----
    if (t < 64) {
      float rwv = 0.f;
      if (t < 16) {
        float x = s_sim[t] / ((s_norm[t] + DELTAF) * (s_rkn + DELTAF)) * s_sc[0];
        float mx = x;
        mx = fmaxf(mx, __shfl_xor(mx,1)); mx = fmaxf(mx, __shfl_xor(mx,2));
        mx = fmaxf(mx, __shfl_xor(mx,4)); mx = fmaxf(mx, __shfl_xor(mx,8));
        float ex = expf(x - mx);
        float sm = ex;
        sm += __shfl_xor(sm,1); sm += __shfl_xor(sm,2); sm += __shfl_xor(sm,4); sm += __shfl_xor(sm,8);
        float cw = ex / sm;
        rwv = s_sc[5]*s_bw[t] + s_sc[6]*s_fw[t] + s_sc[7]*cw;
        s_rw[t] = rwv;
      }
      float a = 0.f;
#pragma unroll
      for (int m = 0; m < 16; ++m) a = fmaf(__shfl(rwv, m), s_mem[m][t], a);
      s_lr[t] = a;
    }
    pb ^= 1;
    __syncthreads();
  }

  float* so = stout + (size_t)e * 1440;
  if (t < 64) { so[t] = s_h[t]; so[64+t] = s_lr[t]; }
  if (t < 16) { so[128+t] = s_rw[t]; so[144+t] = s_norm[t]; }
  { const float* mf = &s_mem[0][0]; for (int i = t; i < 1024; i += 512) so[160+i] = mf[i]; }
  if (t < 256) so[1184+t] = (&s_link[0][0])[t];
}

// ---------------- decoder: 65 sequential steps, both memories in parallel halves ----------------
__global__ __launch_bounds__(512, 2) void dec_kernel(
    const float* __restrict__ Wih, const float* __restrict__ Whh, const float* __restrict__ bhh,
    const float* __restrict__ ifw, const float* __restrict__ ifwb,
    const float* __restrict__ giE, const float* __restrict__ st, float* __restrict__ r12h)
{
  __shared__ __align__(16) float s_h[128];
  __shared__ __align__(16) float s_r12[128];
  __shared__ float s_gi[384], s_gh[384], s_xi[136];
  __shared__ __align__(16) float s_mem[2][16][64];
  __shared__ float s_link[2][16][16];
  __shared__ float s_rw[2][16], s_norm[2][16];
  __shared__ float s_sim[2][16], s_fw[2][16], s_bw[2][16];
  __shared__ float s_rs[2], s_rkn[2];
  __shared__ float s_rm[2][3];
  __shared__ float s_bhh[384], s_ifwb[136];

  const int t = threadIdx.x;

  u32 w1[64], w2[64];  // t<384: Wih row t (r12 part), Whh row t
  u32 w3[64];          // t>=384: ifw row t-384 (rows 0..127)
  u32 w4[32];          // t in [384,400): half-rows of ifw rows 128..135
  if (t < 384) {
    ldrow128pk(w1, Wih + (size_t)t*192 + 64);
    ldrow128pk(w2, Whh + (size_t)t*128);
  } else {
    ldrow128pk(w3, ifw + (size_t)(t-384)*128);
    if (t < 400) {
      int k = t - 384;
      ldrow64pk(w4, ifw + (size_t)(128 + (k>>1))*128 + (k&1)*64);
    }
  }
  if (t < 384) s_bhh[t]  = bhh[t];
  if (t < 136) s_ifwb[t] = ifwb[t];
  if (t < 64) {
    s_h[t]      = st[t];        s_h[64+t]   = st[1440+t];
    s_r12[t]    = st[64+t];     s_r12[64+t] = st[1440+64+t];
  }
  if (t < 16) {
    s_rw[0][t]   = st[128+t];   s_rw[1][t]   = st[1440+128+t];
    s_norm[0][t] = st[144+t];   s_norm[1][t] = st[1440+144+t];
  }
  for (int i = t; i < 1024; i += 512) {
    (&s_mem[0][0][0])[i] = st[160+i];
    (&s_mem[1][0][0])[i] = st[1440+160+i];
  }
  if (t < 256) {
    (&s_link[0][0][0])[t] = st[1184+t];
    (&s_link[1][0][0])[t] = st[1440+1184+t];
  }
  __syncthreads();

  float gcur = (t < 384) ? giE[t] : 0.f;

  for (int it = 0; it < 65; ++it) {
    // ---- P1: gi (r1r2 half) + gh, with giE prefetch ----
    if (t < 384) {
      int nx = (it + 1 < 65) ? (it + 1) : 64;
      float gn = giE[nx*384 + t];
      s_gi[t] = gcur + dotp128(w1, s_r12);
      s_gh[t] = s_bhh[t] + dotp128(w2, s_h);
      gcur = gn;
    }
    __syncthreads();
    // ---- P2: GRU (H=128) ----
    if (t < 128) {
      float r = sigf(s_gi[t] + s_gh[t]);
      float z = sigf(s_gi[128+t] + s_gh[128+t]);
      float n = tanhf(s_gi[256+t] + r*s_gh[256+t]);
      s_h[t] = (1.f - z)*n + z*s_h[t];
    }
    __syncthreads();
    // ---- P3: interface GEMV (rows 0..127 full, rows 128..135 split-halves) ----
    if (t >= 384) {
      s_xi[t-384] = s_ifwb[t-384] + dotp128(w3, s_h);
      if (t < 400) {
        int k = t - 384;
        int row = 128 + (k >> 1);
        float p = dotp64(w4, s_h + (k&1)*64);
        p += __shfl_xor(p, 1);
        if (!(k & 1)) s_xi[row] = s_ifwb[row] + p;
      }
    }
    __syncthreads();
    // ---- S1: per-half sim (raw) + rk norm + fw/bw + scalars ----
    {
      int half = t >> 8, u = t & 255;
      int m = u >> 4, l = u & 15;
      float p = 0.f;
#pragma unroll
      for (int i = 0; i < 4; ++i) {
        float rk = tanhf(s_xi[half*64 + l*4 + i]);
        p = fmaf(rk, s_mem[half][m][l*4+i], p);
      }
      p += __shfl_xor(p,1); p += __shfl_xor(p,2); p += __shfl_xor(p,4); p += __shfl_xor(p,8);
      if (l == 0) s_sim[half][m] = p;   // raw
      if (u < 64) {                      // wave-local 64-lane rk-norm
        float v = tanhf(s_xi[half*64 + u]);
        float q = v*v;
        q += __shfl_xor(q,1); q += __shfl_xor(q,2); q += __shfl_xor(q,4);
        q += __shfl_xor(q,8); q += __shfl_xor(q,16); q += __shfl_xor(q,32);
        if (u == 0) s_rkn[half] = sqrtf(q);
      } else if (u < 80) {
        int i = u - 64;
        float a = 0.f;
#pragma unroll
        for (int j = 0; j < 16; ++j) a = fmaf(s_link[half][i][j], s_rw[half][j], a);
        s_fw[half][i] = a;
      } else if (u < 96) {
        int i = u - 80;
        float a = 0.f;
#pragma unroll
        for (int j = 0; j < 16; ++j) a = fmaf(s_link[half][j][i], s_rw[half][j], a);
        s_bw[half][i] = a;
      } else if (u == 96) {
        s_rs[half] = softplusf(s_xi[128 + half]);
        float a = s_xi[130 + half*3], b = s_xi[131 + half*3], c = s_xi[132 + half*3];
        float mx = fmaxf(a, fmaxf(b, c));
        float ea = expf(a-mx), eb = expf(b-mx), ec = expf(c-mx);
        float s = ea+eb+ec;
        s_rm[half][0] = ea/s; s_rm[half][1] = eb/s; s_rm[half][2] = ec/s;
      }
    }
    __syncthreads();
    // ---- S2: per-half softmax + rw + read vector (waves 0,1); h store (waves 2,3) ----
    if (t < 128) {
      int half = t >> 6, lane = t & 63;
      float rwv = 0.f;
      if (lane < 16) {
        float x = s_sim[half][lane] / ((s_norm[half][lane] + DELTAF)*(s_rkn[half] + DELTAF)) * s_rs[half];
        float mx = x;
        mx = fmaxf(mx, __shfl_xor(mx,1)); mx = fmaxf(mx, __shfl_xor(mx,2));
        mx = fmaxf(mx, __shfl_xor(mx,4)); mx = fmaxf(mx, __shfl_xor(mx,8));
        float ex = expf(x - mx);
        float sm = ex;
        sm += __shfl_xor(sm,1); sm += __shfl_xor(sm,2); sm += __shfl_xor(sm,4); sm += __shfl_xor(sm,8);
        float cw = ex / sm;
        rwv = s_rm[half][0]*s_bw[half][lane] + s_rm[half][1]*s_fw[half][lane] + s_rm[half][2]*cw;
        s_rw[half][lane] = rwv;
      }
      float a = 0.f;
#pragma unroll
      for (int m = 0; m < 16; ++m) a = fmaf(__shfl(rwv, m), s_mem[half][m][t & 63], a);
      s_r12[half*64 + (t&63)] = a;
      r12h[it*256 + half*64 + (t&63)] = a;
    } else if (t < 256) {
      r12h[it*256 + t] = s_h[t - 128];
    }
    __syncthreads();
  }
}

// ---------------- deferred logits ----------------
__global__ void logits_kernel(
    const float* __restrict__ r2oW, const float* __restrict__ r2ob,
    const float* __restrict__ outW, const float* __restrict__ outb,
    const float* __restrict__ r12h, float* __restrict__ out)
{
  __shared__ __align__(16) float s_in[128];
  __shared__ __align__(16) float s_oh[128];
  const int it = blockIdx.x, t = threadIdx.x;
  if (t < 128) s_in[t] = r12h[it*256 + t];
  __syncthreads();
  if (t < 128) {
    float o = r2ob[t] + dotgf(r2oW + (size_t)t*128, s_in, 32);
    s_oh[t] = o + r12h[it*256 + 128 + t];
  }
  __syncthreads();
  if (t < 138) {
    out[it*138 + t] = outb[t] + dotgf(outW + (size_t)t*128, s_oh, 32);
  }
}

extern "C" void kernel_launch(void* const* d_in, const int* in_sizes, int n_in,
                              void* d_out, int out_size, void* d_ws, size_t ws_size,
                              hipStream_t stream) {
  (void)in_sizes; (void)n_in; (void)out_size; (void)ws_size;
  const float* emb0   = (const float*)d_in[0];
  const float* emb1   = (const float*)d_in[1];
  const float* emb2   = (const float*)d_in[2];
  const float* e1_Wih = (const float*)d_in[3];
  const float* e1_Whh = (const float*)d_in[4];
  const float* e1_bih = (const float*)d_in[5];
  const float* e1_bhh = (const float*)d_in[6];
  const float* e1_iW  = (const float*)d_in[7];
  const float* e1_ib  = (const float*)d_in[8];
  const float* e2_Wih = (const float*)d_in[9];
  const float* e2_Whh = (const float*)d_in[10];
  const float* e2_bih = (const float*)d_in[11];
  const float* e2_bhh = (const float*)d_in[12];
  const float* e2_iW  = (const float*)d_in[13];
  const float* e2_ib  = (const float*)d_in[14];
  const float* dWih   = (const float*)d_in[15];
  const float* dWhh   = (const float*)d_in[16];
  const float* dbih   = (const float*)d_in[17];
  const float* dbhh   = (const float*)d_in[18];
  const float* ifwW   = (const float*)d_in[19];
  const float* ifwb   = (const float*)d_in[20];
  const float* r2oW   = (const float*)d_in[21];
  const float* r2ob   = (const float*)d_in[22];
  const float* outW   = (const float*)d_in[23];
  const float* outb   = (const float*)d_in[24];
  const int* seq1     = (const int*)d_in[25];
  const int* seq2     = (const int*)d_in[26];
  const int* seq3     = (const int*)d_in[27];

  float* ws   = (float*)d_ws;
  float* giE1 = ws;                    // 512*192
  float* giE2 = giE1 + 512*192;        // 512*192 (contiguous with giE1)
  float* giEd = giE2 + 512*192;        // 65*384
  float* st   = giEd + 65*384;         // 2*1440
  float* r12h = st + 2*1440;           // 65*256

  prep_enc<<<512, 192, 0, stream>>>(emb0, seq1, e1_Wih, e1_bih, giE1);
  prep_enc<<<512, 192, 0, stream>>>(emb1, seq2, e2_Wih, e2_bih, giE2);
  prep_dec<<<65, 384, 0, stream>>>(emb2, seq3, dWih, dbih, giEd);
  enc_kernel<<<2, 512, 0, stream>>>(e1_Wih, e1_Whh, e1_bhh, e1_iW, e1_ib,
                                    e2_Wih, e2_Whh, e2_bhh, e2_iW, e2_ib, giE1, st);
  dec_kernel<<<1, 512, 0, stream>>>(dWih, dWhh, dbhh, ifwW, ifwb, giEd, st, r12h);
  logits_kernel<<<65, 256, 0, stream>>>(r2oW, r2ob, outW, outb, r12h, (float*)d_out);
}

// Round 4
// 4178.924 us; speedup vs baseline: 1.1088x; 1.0121x over previous
//
#include <hip/hip_runtime.h>
#include <hip/hip_bf16.h>
#include <stdint.h>

typedef uint32_t u32;

#define DELTAF 1e-6f
#define CLIPF 20.0f

__device__ __forceinline__ float bl(u32 u) { return __uint_as_float(u << 16); }
__device__ __forceinline__ float bh(u32 u) { return __uint_as_float(u & 0xffff0000u); }

__device__ __forceinline__ float sigf(float x) { return 1.f / (1.f + expf(-x)); }
__device__ __forceinline__ float softplusf(float x) { return fmaxf(x, 0.f) + log1pf(expf(-fabsf(x))); }

// f32 -> bf16 bits, round-to-nearest-even
__device__ __forceinline__ u32 f2b(float f) {
  u32 b = __float_as_uint(f);
  return (b + 0x7fffu + ((b >> 16) & 1u)) >> 16;
}

// load 64 consecutive f32 into registers
__device__ __forceinline__ void ldrow64f(float* wf, const float* p) {
  const float4* q = (const float4*)p;
#pragma unroll
  for (int i = 0; i < 16; ++i) {
    float4 v = q[i];
    wf[4*i+0] = v.x; wf[4*i+1] = v.y; wf[4*i+2] = v.z; wf[4*i+3] = v.w;
  }
}

// load 128 consecutive f32 -> bf16 RNE, pack pairs into 64 u32
__device__ __forceinline__ void ldrow128pk(u32* w, const float* p) {
  const float4* q = (const float4*)p;
#pragma unroll
  for (int i = 0; i < 32; ++i) {
    float4 v = q[i];
    w[2*i]   = f2b(v.x) | (f2b(v.y) << 16);
    w[2*i+1] = f2b(v.z) | (f2b(v.w) << 16);
  }
}

// load 64 consecutive f32 -> bf16 RNE, pack into 32 u32
__device__ __forceinline__ void ldrow64pk(u32* w, const float* p) {
  const float4* q = (const float4*)p;
#pragma unroll
  for (int i = 0; i < 16; ++i) {
    float4 v = q[i];
    w[2*i]   = f2b(v.x) | (f2b(v.y) << 16);
    w[2*i+1] = f2b(v.z) | (f2b(v.w) << 16);
  }
}

// 64-long dot, f32 weights in regs, 4 accumulators
__device__ __forceinline__ float dotf64(const float* w, const float* x) {
  float a0 = 0.f, a1 = 0.f, a2 = 0.f, a3 = 0.f;
#pragma unroll
  for (int i = 0; i < 16; i += 4) {
    float4 v0 = ((const float4*)x)[i+0];
    float4 v1 = ((const float4*)x)[i+1];
    float4 v2 = ((const float4*)x)[i+2];
    float4 v3 = ((const float4*)x)[i+3];
    a0 = fmaf(w[4*i+ 0], v0.x, a0); a0 = fmaf(w[4*i+ 1], v0.y, a0);
    a0 = fmaf(w[4*i+ 2], v0.z, a0); a0 = fmaf(w[4*i+ 3], v0.w, a0);
    a1 = fmaf(w[4*i+ 4], v1.x, a1); a1 = fmaf(w[4*i+ 5], v1.y, a1);
    a1 = fmaf(w[4*i+ 6], v1.z, a1); a1 = fmaf(w[4*i+ 7], v1.w, a1);
    a2 = fmaf(w[4*i+ 8], v2.x, a2); a2 = fmaf(w[4*i+ 9], v2.y, a2);
    a2 = fmaf(w[4*i+10], v2.z, a2); a2 = fmaf(w[4*i+11], v2.w, a2);
    a3 = fmaf(w[4*i+12], v3.x, a3); a3 = fmaf(w[4*i+13], v3.y, a3);
    a3 = fmaf(w[4*i+14], v3.z, a3); a3 = fmaf(w[4*i+15], v3.w, a3);
  }
  return (a0 + a1) + (a2 + a3);
}

// 128-long dot, packed bf16 weights in regs, 4 accumulators
__device__ __forceinline__ float dotp128(const u32* w, const float* x) {
  float a0 = 0.f, a1 = 0.f, a2 = 0.f, a3 = 0.f;
#pragma unroll
  for (int i = 0; i < 8; ++i) {
    float4 v0 = ((const float4*)x)[4*i+0];
    float4 v1 = ((const float4*)x)[4*i+1];
    float4 v2 = ((const float4*)x)[4*i+2];
    float4 v3 = ((const float4*)x)[4*i+3];
    u32 p0 = w[8*i+0], q0 = w[8*i+1], p1 = w[8*i+2], q1 = w[8*i+3];
    u32 p2 = w[8*i+4], q2 = w[8*i+5], p3 = w[8*i+6], q3 = w[8*i+7];
    a0 = fmaf(bl(p0), v0.x, a0); a0 = fmaf(bh(p0), v0.y, a0);
    a0 = fmaf(bl(q0), v0.z, a0); a0 = fmaf(bh(q0), v0.w, a0);
    a1 = fmaf(bl(p1), v1.x, a1); a1 = fmaf(bh(p1), v1.y, a1);
    a1 = fmaf(bl(q1), v1.z, a1); a1 = fmaf(bh(q1), v1.w, a1);
    a2 = fmaf(bl(p2), v2.x, a2); a2 = fmaf(bh(p2), v2.y, a2);
    a2 = fmaf(bl(q2), v2.z, a2); a2 = fmaf(bh(q2), v2.w, a2);
    a3 = fmaf(bl(p3), v3.x, a3); a3 = fmaf(bh(p3), v3.y, a3);
    a3 = fmaf(bl(q3), v3.z, a3); a3 = fmaf(bh(q3), v3.w, a3);
  }
  return (a0 + a1) + (a2 + a3);
}

// 64-long dot, packed bf16 weights (32 u32), 2 accumulators
__device__ __forceinline__ float dotp64(const u32* w, const float* x) {
  float a0 = 0.f, a1 = 0.f;
#pragma unroll
  for (int i = 0; i < 8; ++i) {
    float4 v0 = ((const float4*)x)[2*i+0];
    float4 v1 = ((const float4*)x)[2*i+1];
    u32 p0 = w[4*i+0], q0 = w[4*i+1], p1 = w[4*i+2], q1 = w[4*i+3];
    a0 = fmaf(bl(p0), v0.x, a0); a0 = fmaf(bh(p0), v0.y, a0);
    a0 = fmaf(bl(q0), v0.z, a0); a0 = fmaf(bh(q0), v0.w, a0);
    a1 = fmaf(bl(p1), v1.x, a1); a1 = fmaf(bh(p1), v1.y, a1);
    a1 = fmaf(bl(q1), v1.z, a1); a1 = fmaf(bh(q1), v1.w, a1);
  }
  return a0 + a1;
}

// dot over 4*n4 elements, f32 weights streamed from global
__device__ __forceinline__ float dotgf(const float* row, const float* x, int n4) {
  float a = 0.f;
  for (int i = 0; i < n4; ++i) {
    float4 w = ((const float4*)row)[i];
    float4 xv = ((const float4*)x)[i];
    a = fmaf(w.x, xv.x, a);
    a = fmaf(w.y, xv.y, a);
    a = fmaf(w.z, xv.z, a);
    a = fmaf(w.w, xv.w, a);
  }
  return a;
}

// ---------------- prep kernels ----------------
__global__ void prep_enc(const float* __restrict__ emb, const int* __restrict__ seq,
                         const float* __restrict__ Wih, const float* __restrict__ bih,
                         float* __restrict__ giE)
{
  __shared__ __align__(16) float sx[64];
  const int it = blockIdx.x, t = threadIdx.x;
  if (t < 64) sx[t] = emb[(size_t)seq[it]*64 + t];
  __syncthreads();
  if (t < 192) giE[it*192 + t] = bih[t] + dotgf(Wih + (size_t)t*128, sx, 16);
}

__global__ void prep_dec(const float* __restrict__ emb2, const int* __restrict__ seq3,
                         const float* __restrict__ Wih, const float* __restrict__ bih,
                         float* __restrict__ giE)
{
  __shared__ __align__(16) float sx[64];
  const int it = blockIdx.x, t = threadIdx.x;
  const int tok = (it == 0) ? 136 : seq3[it-1];
  if (t < 64) sx[t] = emb2[(size_t)tok*64 + t];
  __syncthreads();
  if (t < 384) giE[it*384 + t] = bih[t] + dotgf(Wih + (size_t)t*192, sx, 16);
}

// ---------------- encoder: 512 sequential DNC steps, 1 block per encoder ----------------
// stout layout per encoder (1440 f32):
//  [0,64) h | [64,128) lr | [128,144) rw | [144,160) mem row norms | [160,1184) mem | [1184,1440) link
__global__ __launch_bounds__(512, 1) void enc_kernel(
    const float* __restrict__ Wih1, const float* __restrict__ Whh1, const float* __restrict__ bhh1,
    const float* __restrict__ iW1, const float* __restrict__ ib1,
    const float* __restrict__ Wih2, const float* __restrict__ Whh2, const float* __restrict__ bhh2,
    const float* __restrict__ iW2, const float* __restrict__ ib2,
    const float* __restrict__ giE_all, float* __restrict__ stout)
{
  __shared__ __align__(16) float s_h[64];
  __shared__ __align__(16) float s_hc[64];
  __shared__ __align__(16) float s_lr[64];
  __shared__ float s_gi[192], s_gh[192], s_xi[264];
  __shared__ __align__(16) float s_mem[16][64];
  __shared__ float s_link[16][16];
  __shared__ float s_prec[2][16];
  __shared__ __align__(16) float s_rw[16];
  __shared__ __align__(16) float s_ww[16];
  __shared__ __align__(16) float s_usage[16];
  __shared__ float s_norm[16], s_sim[16], s_fw[16], s_bw[16];
  __shared__ float s_ev[64], s_wv[64];
  __shared__ float s_sc[8]; // 0:rs 1:ws 3:ag 4:wg 5..7:rm
  __shared__ float s_bhh[192], s_ib[264];
  __shared__ float s_wkn, s_rkn, s_S;

  const int t = threadIdx.x;
  const int e = blockIdx.x;
  const float* Wih = e ? Wih2 : Wih1;
  const float* Whh = e ? Whh2 : Whh1;
  const float* bhh = e ? bhh2 : bhh1;
  const float* iW  = e ? iW2  : iW1;
  const float* ib  = e ? ib2  : ib1;
  const float* giE = giE_all + (size_t)e * 512 * 192;

  float w1[64];  // f32: t<192: Wih row t cols 64..127 ; t in [192,384): Whh row t-192
  u32   w2[32];  // bf16-packed: t<264: iW row t
  if (t < 192)      ldrow64f(w1, Wih + (size_t)t*128 + 64);
  else if (t < 384) ldrow64f(w1, Whh + (size_t)(t-192)*64);
  if (t < 264)      ldrow64pk(w2, iW + (size_t)t*64);

  if (t < 192) s_bhh[t] = bhh[t];
  if (t < 264) s_ib[t]  = ib[t];
  if (t < 64) { s_h[t] = 0.f; s_lr[t] = 0.f; }
  if (t < 16) {
    s_rw[t] = DELTAF; s_ww[t] = DELTAF; s_usage[t] = 0.f; s_norm[t] = 0.f;
    s_prec[0][t] = 0.f; s_prec[1][t] = 0.f;
  }
  { float* mf = &s_mem[0][0]; for (int i = t; i < 1024; i += 512) mf[i] = 0.f; }
  if (t < 256) (&s_link[0][0])[t] = 0.f;
  __syncthreads();

  float gcur = (t < 192) ? giE[t] : 0.f;   // prefetched gi_emb for step 0
  int pb = 0;

  for (int it = 0; it < 512; ++it) {
    // ---- P1: gi (lr half) and gh GEMVs, register-resident weights ----
    if (t < 192) {
      int nx = (it + 1 < 512) ? (it + 1) : 511;
      float gn = giE[nx*192 + t];              // prefetch next step (latency hidden)
      s_gi[t] = gcur + dotf64(w1, s_lr);
      gcur = gn;
    } else if (t < 384) {
      s_gh[t-192] = s_bhh[t-192] + dotf64(w1, s_h);
    }
    __syncthreads();
    // ---- P2: GRU combine ----
    if (t < 64) {
      float r = sigf(s_gi[t] + s_gh[t]);
      float z = sigf(s_gi[64+t] + s_gh[64+t]);
      float n = tanhf(s_gi[128+t] + r*s_gh[128+t]);
      float h = (1.f - z)*n + z*s_h[t];
      s_h[t] = h;
      s_hc[t] = fminf(fmaxf(h, -CLIPF), CLIPF);
    }
    __syncthreads();
    // ---- P3: interface GEMV (bf16 weights) ----
    if (t < 264) s_xi[t] = s_ib[t] + dotp64(w2, s_hc);
    __syncthreads();
    // ---- S1: write-key sim (raw) + activations + key norms + usage + scalars ----
    {
      int m = t >> 5, l = t & 31;
      float wkl = tanhf(s_xi[65+l]);
      float wkh = tanhf(s_xi[65+32+l]);
      float p = fmaf(wkl, s_mem[m][l], wkh * s_mem[m][l+32]);
      p += __shfl_xor(p,1); p += __shfl_xor(p,2); p += __shfl_xor(p,4);
      p += __shfl_xor(p,8); p += __shfl_xor(p,16);
      if (l == 0) s_sim[m] = p;   // raw dot; normalized in S2
    }
    if (t < 64) {
      s_ev[t] = sigf(s_xi[130+t]);
      s_wv[t] = tanhf(s_xi[194+t]);
    } else if (t < 128) {
      int l = t - 64;                       // wave 1: read-key norm
      float v = tanhf(s_xi[l]);
      float p = v*v;
      p += __shfl_xor(p,1); p += __shfl_xor(p,2); p += __shfl_xor(p,4);
      p += __shfl_xor(p,8); p += __shfl_xor(p,16); p += __shfl_xor(p,32);
      if (l == 0) s_rkn = sqrtf(p);
    } else if (t < 192) {
      int l = t - 128;                      // wave 2: write-key norm
      float v = tanhf(s_xi[65+l]);
      float p = v*v;
      p += __shfl_xor(p,1); p += __shfl_xor(p,2); p += __shfl_xor(p,4);
      p += __shfl_xor(p,8); p += __shfl_xor(p,16); p += __shfl_xor(p,32);
      if (l == 0) s_wkn = sqrtf(p);
    } else if (t < 208) {
      int j = t - 192;                      // usage update (prev ww, prev rw, this fg)
      float fg = sigf(s_xi[258]);
      float u = s_usage[j];
      u = u + (1.f - u) * s_ww[j];
      u = u * (1.f - fg * s_rw[j]);
      s_usage[j] = u;
    } else if (t == 208) s_sc[0] = softplusf(s_xi[64]);
    else if (t == 209) s_sc[1] = softplusf(s_xi[129]);
    else if (t == 210) s_sc[3] = sigf(s_xi[259]);
    else if (t == 211) s_sc[4] = sigf(s_xi[260]);
    else if (t == 212) {
      float a = s_xi[261], b = s_xi[262], c = s_xi[263];
      float mx = fmaxf(a, fmaxf(b, c));
      float ea = expf(a-mx), eb = expf(b-mx), ec = expf(c-mx);
      float s = ea + eb + ec;
      s_sc[5] = ea/s; s_sc[6] = eb/s; s_sc[7] = ec/s;
    }
    __syncthreads();
    // ---- S2: write softmax + allocation + write weights (wave 0, lanes 0..15) ----
    if (t < 16) {
      float x = s_sim[t] / ((s_norm[t] + DELTAF) * (s_wkn + DELTAF)) * s_sc[1];
      float mx = x;
      mx = fmaxf(mx, __shfl_xor(mx,1)); mx = fmaxf(mx, __shfl_xor(mx,2));
      mx = fmaxf(mx, __shfl_xor(mx,4)); mx = fmaxf(mx, __shfl_xor(mx,8));
      float ex = expf(x - mx);
      float sm = ex;
      sm += __shfl_xor(sm,1); sm += __shfl_xor(sm,2); sm += __shfl_xor(sm,4); sm += __shfl_xor(sm,8);
      float wcw = ex / sm;
      float4 u0 = ((const float4*)s_usage)[0];
      float4 u1 = ((const float4*)s_usage)[1];
      float4 u2 = ((const float4*)s_usage)[2];
      float4 u3 = ((const float4*)s_usage)[3];
      float uj[16] = {u0.x,u0.y,u0.z,u0.w, u1.x,u1.y,u1.z,u1.w,
                      u2.x,u2.y,u2.z,u2.w, u3.x,u3.y,u3.z,u3.w};
      float um = DELTAF + (1.f - DELTAF) * s_usage[t];
      float prod = 1.f;
#pragma unroll
      for (int j = 0; j < 16; ++j) {
        float v = DELTAF + (1.f - DELTAF) * uj[j];
        bool before = (v < um) || ((v == um) && (j < t));  // stable argsort order
        prod *= before ? v : 1.f;
      }
      float alloc = (1.f - um) * prod;
      float ww = s_sc[4] * (s_sc[3]*alloc + (1.f - s_sc[3])*wcw);
      float S = ww;
      S += __shfl_xor(S,1); S += __shfl_xor(S,2); S += __shfl_xor(S,4); S += __shfl_xor(S,8);
      s_ww[t] = ww;
      if (t == 0) s_S = S;
    }
    __syncthreads();
    // ---- S3: memory write + link update (+in-register fw) + precedence ----
    {
#pragma unroll
      for (int q = 0; q < 2; ++q) {
        int idx = t + q*512;
        int m = idx >> 6, wi = idx & 63;
        float wwm = s_ww[m];
        s_mem[m][wi] = s_mem[m][wi] * (1.f - wwm * s_ev[wi]) + wwm * s_wv[wi];
      }
    }
    if (t < 256) {
      int i = t >> 4, j = t & 15;
      float lv = (i == j) ? 0.f
               : ((1.f - s_ww[i] - s_ww[j]) * s_link[i][j] + s_ww[i] * s_prec[pb][j]);
      s_link[i][j] = lv;
      // fw_i = sum_j lv * rw_old[j]  (16-lane subgroup reduce, wave-local)
      float p = lv * s_rw[j];
      p += __shfl_xor(p,1); p += __shfl_xor(p,2); p += __shfl_xor(p,4); p += __shfl_xor(p,8);
      if (j == 0) s_fw[i] = p;
    } else if (t < 272) {
      int j = t - 256;
      s_prec[pb^1][j] = (1.f - s_S) * s_prec[pb][j] + s_ww[j];
    }
    __syncthreads();
    // ---- S4: read-key sim (raw) + post-write norms (dual reduce) + bw ----
    {
      int m = t >> 5, l = t & 31;
      float rkl = tanhf(s_xi[l]);
      float rkh = tanhf(s_xi[l+32]);
      float ml = s_mem[m][l], mh = s_mem[m][l+32];
      float p = fmaf(rkl, ml, rkh * mh);
      float q = fmaf(ml, ml, mh * mh);
      p += __shfl_xor(p,1);  q += __shfl_xor(q,1);
      p += __shfl_xor(p,2);  q += __shfl_xor(q,2);
      p += __shfl_xor(p,4);  q += __shfl_xor(q,4);
      p += __shfl_xor(p,8);  q += __shfl_xor(q,8);
      p += __shfl_xor(p,16); q += __shfl_xor(q,16);
      if (l == 0) { s_sim[m] = p; s_norm[m] = sqrtf(q); }  // s_norm now = post-write norm (carried)
    }
    if (t >= 496) {
      int i = t - 496;   // bw_i = sum_j link[j][i] * rw_old[j]
      float a = 0.f;
#pragma unroll
      for (int j = 0; j < 16; ++j) a = fmaf(s_link[j][i], s_rw[j], a);
      s_bw[i] = a;
    }
    __syncthreads();
    // ---- S5: read softmax + read weights + read vector (wave 0) ----
    if (t < 64) {
      float rwv = 0.f;
      if (t < 16) {
        float x = s_sim[t] / ((s_norm[t] + DELTAF) * (s_rkn + DELTAF)) * s_sc[0];
        float mx = x;
        mx = fmaxf(mx, __shfl_xor(mx,1)); mx = fmaxf(mx, __shfl_xor(mx,2));
        mx = fmaxf(mx, __shfl_xor(mx,4)); mx = fmaxf(mx, __shfl_xor(mx,8));
        float ex = expf(x - mx);
        float sm = ex;
        sm += __shfl_xor(sm,1); sm += __shfl_xor(sm,2); sm += __shfl_xor(sm,4); sm += __shfl_xor(sm,8);
        float cw = ex / sm;
        rwv = s_sc[5]*s_bw[t] + s_sc[6]*s_fw[t] + s_sc[7]*cw;
        s_rw[t] = rwv;
      }
      float a = 0.f;
#pragma unroll
      for (int m = 0; m < 16; ++m) a = fmaf(__shfl(rwv, m), s_mem[m][t], a);
      s_lr[t] = a;
    }
    pb ^= 1;
    __syncthreads();
  }

  float* so = stout + (size_t)e * 1440;
  if (t < 64) { so[t] = s_h[t]; so[64+t] = s_lr[t]; }
  if (t < 16) { so[128+t] = s_rw[t]; so[144+t] = s_norm[t]; }
  { const float* mf = &s_mem[0][0]; for (int i = t; i < 1024; i += 512) so[160+i] = mf[i]; }
  if (t < 256) so[1184+t] = (&s_link[0][0])[t];
}

// ---------------- decoder: 65 sequential steps, both memories in parallel halves ----------------
__global__ __launch_bounds__(512, 1) void dec_kernel(
    const float* __restrict__ Wih, const float* __restrict__ Whh, const float* __restrict__ bhh,
    const float* __restrict__ ifw, const float* __restrict__ ifwb,
    const float* __restrict__ giE, const float* __restrict__ st, float* __restrict__ r12h)
{
  __shared__ __align__(16) float s_h[128];
  __shared__ __align__(16) float s_r12[128];
  __shared__ float s_gi[384], s_gh[384], s_xi[136];
  __shared__ __align__(16) float s_mem[2][16][64];
  __shared__ float s_link[2][16][16];
  __shared__ float s_rw[2][16], s_norm[2][16];
  __shared__ float s_sim[2][16], s_fw[2][16], s_bw[2][16];
  __shared__ float s_rs[2], s_rkn[2];
  __shared__ float s_rm[2][3];
  __shared__ float s_bhh[384], s_ifwb[136];

  const int t = threadIdx.x;

  u32 w1[64], w2[64];  // t<384: Wih row t (r12 part), Whh row t
  u32 w3[64];          // t>=384: ifw row t-384 (rows 0..127)
  u32 w4[32];          // t in [384,400): half-rows of ifw rows 128..135
  if (t < 384) {
    ldrow128pk(w1, Wih + (size_t)t*192 + 64);
    ldrow128pk(w2, Whh + (size_t)t*128);
  } else {
    ldrow128pk(w3, ifw + (size_t)(t-384)*128);
    if (t < 400) {
      int k = t - 384;
      ldrow64pk(w4, ifw + (size_t)(128 + (k>>1))*128 + (k&1)*64);
    }
  }
  if (t < 384) s_bhh[t]  = bhh[t];
  if (t < 136) s_ifwb[t] = ifwb[t];
  if (t < 64) {
    s_h[t]      = st[t];        s_h[64+t]   = st[1440+t];
    s_r12[t]    = st[64+t];     s_r12[64+t] = st[1440+64+t];
  }
  if (t < 16) {
    s_rw[0][t]   = st[128+t];   s_rw[1][t]   = st[1440+128+t];
    s_norm[0][t] = st[144+t];   s_norm[1][t] = st[1440+144+t];
  }
  for (int i = t; i < 1024; i += 512) {
    (&s_mem[0][0][0])[i] = st[160+i];
    (&s_mem[1][0][0])[i] = st[1440+160+i];
  }
  if (t < 256) {
    (&s_link[0][0][0])[t] = st[1184+t];
    (&s_link[1][0][0])[t] = st[1440+1184+t];
  }
  __syncthreads();

  float gcur = (t < 384) ? giE[t] : 0.f;

  for (int it = 0; it < 65; ++it) {
    // ---- P1: gi (r1r2 half) + gh, with giE prefetch ----
    if (t < 384) {
      int nx = (it + 1 < 65) ? (it + 1) : 64;
      float gn = giE[nx*384 + t];
      s_gi[t] = gcur + dotp128(w1, s_r12);
      s_gh[t] = s_bhh[t] + dotp128(w2, s_h);
      gcur = gn;
    }
    __syncthreads();
    // ---- P2: GRU (H=128) ----
    if (t < 128) {
      float r = sigf(s_gi[t] + s_gh[t]);
      float z = sigf(s_gi[128+t] + s_gh[128+t]);
      float n = tanhf(s_gi[256+t] + r*s_gh[256+t]);
      s_h[t] = (1.f - z)*n + z*s_h[t];
    }
    __syncthreads();
    // ---- P3: interface GEMV (rows 0..127 full, rows 128..135 split-halves) ----
    if (t >= 384) {
      s_xi[t-384] = s_ifwb[t-384] + dotp128(w3, s_h);
      if (t < 400) {
        int k = t - 384;
        int row = 128 + (k >> 1);
        float p = dotp64(w4, s_h + (k&1)*64);
        p += __shfl_xor(p, 1);
        if (!(k & 1)) s_xi[row] = s_ifwb[row] + p;
      }
    }
    __syncthreads();
    // ---- S1: per-half sim (raw) + rk norm + fw/bw + scalars ----
    {
      int half = t >> 8, u = t & 255;
      int m = u >> 4, l = u & 15;
      float p = 0.f;
#pragma unroll
      for (int i = 0; i < 4; ++i) {
        float rk = tanhf(s_xi[half*64 + l*4 + i]);
        p = fmaf(rk, s_mem[half][m][l*4+i], p);
      }
      p += __shfl_xor(p,1); p += __shfl_xor(p,2); p += __shfl_xor(p,4); p += __shfl_xor(p,8);
      if (l == 0) s_sim[half][m] = p;   // raw
      if (u < 64) {                      // wave-local 64-lane rk-norm
        float v = tanhf(s_xi[half*64 + u]);
        float q = v*v;
        q += __shfl_xor(q,1); q += __shfl_xor(q,2); q += __shfl_xor(q,4);
        q += __shfl_xor(q,8); q += __shfl_xor(q,16); q += __shfl_xor(q,32);
        if (u == 0) s_rkn[half] = sqrtf(q);
      } else if (u < 80) {
        int i = u - 64;
        float a = 0.f;
#pragma unroll
        for (int j = 0; j < 16; ++j) a = fmaf(s_link[half][i][j], s_rw[half][j], a);
        s_fw[half][i] = a;
      } else if (u < 96) {
        int i = u - 80;
        float a = 0.f;
#pragma unroll
        for (int j = 0; j < 16; ++j) a = fmaf(s_link[half][j][i], s_rw[half][j], a);
        s_bw[half][i] = a;
      } else if (u == 96) {
        s_rs[half] = softplusf(s_xi[128 + half]);
        float a = s_xi[130 + half*3], b = s_xi[131 + half*3], c = s_xi[132 + half*3];
        float mx = fmaxf(a, fmaxf(b, c));
        float ea = expf(a-mx), eb = expf(b-mx), ec = expf(c-mx);
        float s = ea+eb+ec;
        s_rm[half][0] = ea/s; s_rm[half][1] = eb/s; s_rm[half][2] = ec/s;
      }
    }
    __syncthreads();
    // ---- S2: per-half softmax + rw + read vector (waves 0,1); h store (waves 2,3) ----
    if (t < 128) {
      int half = t >> 6, lane = t & 63;
      float rwv = 0.f;
      if (lane < 16) {
        float x = s_sim[half][lane] / ((s_norm[half][lane] + DELTAF)*(s_rkn[half] + DELTAF)) * s_rs[half];
        float mx = x;
        mx = fmaxf(mx, __shfl_xor(mx,1)); mx = fmaxf(mx, __shfl_xor(mx,2));
        mx = fmaxf(mx, __shfl_xor(mx,4)); mx = fmaxf(mx, __shfl_xor(mx,8));
        float ex = expf(x - mx);
        float sm = ex;
        sm += __shfl_xor(sm,1); sm += __shfl_xor(sm,2); sm += __shfl_xor(sm,4); sm += __shfl_xor(sm,8);
        float cw = ex / sm;
        rwv = s_rm[half][0]*s_bw[half][lane] + s_rm[half][1]*s_fw[half][lane] + s_rm[half][2]*cw;
        s_rw[half][lane] = rwv;
      }
      float a = 0.f;
#pragma unroll
      for (int m = 0; m < 16; ++m) a = fmaf(__shfl(rwv, m), s_mem[half][m][t & 63], a);
      s_r12[half*64 + (t&63)] = a;
      r12h[it*256 + half*64 + (t&63)] = a;
    } else if (t < 256) {
      r12h[it*256 + t] = s_h[t - 128];
    }
    __syncthreads();
  }
}

// ---------------- deferred logits ----------------
__global__ void logits_kernel(
    const float* __restrict__ r2oW, const float* __restrict__ r2ob,
    const float* __restrict__ outW, const float* __restrict__ outb,
    const float* __restrict__ r12h, float* __restrict__ out)
{
  __shared__ __align__(16) float s_in[128];
  __shared__ __align__(16) float s_oh[128];
  const int it = blockIdx.x, t = threadIdx.x;
  if (t < 128) s_in[t] = r12h[it*256 + t];
  __syncthreads();
  if (t < 128) {
    float o = r2ob[t] + dotgf(r2oW + (size_t)t*128, s_in, 32);
    s_oh[t] = o + r12h[it*256 + 128 + t];
  }
  __syncthreads();
  if (t < 138) {
    out[it*138 + t] = outb[t] + dotgf(outW + (size_t)t*128, s_oh, 32);
  }
}

extern "C" void kernel_launch(void* const* d_in, const int* in_sizes, int n_in,
                              void* d_out, int out_size, void* d_ws, size_t ws_size,
                              hipStream_t stream) {
  (void)in_sizes; (void)n_in; (void)out_size; (void)ws_size;
  const float* emb0   = (const float*)d_in[0];
  const float* emb1   = (const float*)d_in[1];
  const float* emb2   = (const float*)d_in[2];
  const float* e1_Wih = (const float*)d_in[3];
  const float* e1_Whh = (const float*)d_in[4];
  const float* e1_bih = (const float*)d_in[5];
  const float* e1_bhh = (const float*)d_in[6];
  const float* e1_iW  = (const float*)d_in[7];
  const float* e1_ib  = (const float*)d_in[8];
  const float* e2_Wih = (const float*)d_in[9];
  const float* e2_Whh = (const float*)d_in[10];
  const float* e2_bih = (const float*)d_in[11];
  const float* e2_bhh = (const float*)d_in[12];
  const float* e2_iW  = (const float*)d_in[13];
  const float* e2_ib  = (const float*)d_in[14];
  const float* dWih   = (const float*)d_in[15];
  const float* dWhh   = (const float*)d_in[16];
  const float* dbih   = (const float*)d_in[17];
  const float* dbhh   = (const float*)d_in[18];
  const float* ifwW   = (const float*)d_in[19];
  const float* ifwb   = (const float*)d_in[20];
  const float* r2oW   = (const float*)d_in[21];
  const float* r2ob   = (const float*)d_in[22];
  const float* outW   = (const float*)d_in[23];
  const float* outb   = (const float*)d_in[24];
  const int* seq1     = (const int*)d_in[25];
  const int* seq2     = (const int*)d_in[26];
  const int* seq3     = (const int*)d_in[27];

  float* ws   = (float*)d_ws;
  float* giE1 = ws;                    // 512*192
  float* giE2 = giE1 + 512*192;        // 512*192 (contiguous with giE1)
  float* giEd = giE2 + 512*192;        // 65*384
  float* st   = giEd + 65*384;         // 2*1440
  float* r12h = st + 2*1440;           // 65*256

  prep_enc<<<512, 192, 0, stream>>>(emb0, seq1, e1_Wih, e1_bih, giE1);
  prep_enc<<<512, 192, 0, stream>>>(emb1, seq2, e2_Wih, e2_bih, giE2);
  prep_dec<<<65, 384, 0, stream>>>(emb2, seq3, dWih, dbih, giEd);
  enc_kernel<<<2, 512, 0, stream>>>(e1_Wih, e1_Whh, e1_bhh, e1_iW, e1_ib,
                                    e2_Wih, e2_Whh, e2_bhh, e2_iW, e2_ib, giE1, st);
  dec_kernel<<<1, 512, 0, stream>>>(dWih, dWhh, dbhh, ifwW, ifwb, giEd, st, r12h);
  logits_kernel<<<65, 256, 0, stream>>>(r2oW, r2ob, outW, outb, r12h, (float*)d_out);
}